// Round 6
// baseline (27686.429 us; speedup 1.0000x reference)
//
#include <hip/hip_runtime.h>
#include <math.h>

// NTM recurrence. GEMMs via 3-product 2-plane bf16-split MFMA (~2^-17 rel err per GEMM,
// fp32 state masters). T-loop inside ONE persistent kernel (512 blocks, 2/CU co-resident).
// Coherence scheme (r5/r6): ALL shared stores are sc1 write-through (MALL always current,
// L2 never dirty); reads are NORMAL CACHED; each block runs one acquire-fence (buffer_inv,
// no wbl2) per barrier so post-barrier reads refill from MALL and then hit L2.
// Tiles are XCD-swizzled (xcd=bid%8 heuristic, perf-only) to share B-slices within an XCD.
// B=256 T=128 I=512 H=512 N=1024 M=512 O=512
#define B_ 256
#define T_ 128
#define I_ 512
#define H_ 512
#define N_ 1024
#define M_ 512
#define O_ 512
#define EPS_ 1e-8f
#define NB_ 512  // persistent grid: 512 blocks x 256 thr, 2 blocks/CU co-resident

typedef unsigned short u16;
typedef __attribute__((ext_vector_type(8))) short v8s;   // 8 bf16 = 4 VGPRs
typedef __attribute__((ext_vector_type(4))) float v4f;   // MFMA acc

#define MFMA(a, b, c) __builtin_amdgcn_mfma_f32_16x16x32_bf16(a, b, c, 0, 0, 0)

// plane strides (elements)
#define PL_BIG 1310720  // BigT [2560][512]: rows 0-511 Whw_k, 512-1023 Whr_k, 1024-1535 Wo, 1536-2559 Wea
#define PL_WXT 262144   // WxT  [512][512]
#define PL_WRT 262144   // WrT  [512][512]
#define PL_MEM 524288   // mem  [1024][512] / memT [512][1024]
#define PL_W   262144   // wwT [1024][256] / wr [256][1024]
#define PL_H   131072   // h [256][512], r [256][512], eT/aT [512][256]
#define PL_KH  262144   // kh [512][512]

// ---------------- sc1 (write-through, agent-coherent) store helpers ----------------
template <typename T>
__device__ __forceinline__ void sta_(T* p, T v) {
    __hip_atomic_store(p, v, __ATOMIC_RELAXED, __HIP_MEMORY_SCOPE_AGENT);
}
__device__ __forceinline__ void st64_(u16* p, u16 a, u16 b, u16 c, u16 d) {
    unsigned long long v = (unsigned long long)a | ((unsigned long long)b << 16) |
                           ((unsigned long long)c << 32) | ((unsigned long long)d << 48);
    __hip_atomic_store((unsigned long long*)p, v, __ATOMIC_RELAXED, __HIP_MEMORY_SCOPE_AGENT);
}

// ---------------- scalar helpers ----------------
__device__ __forceinline__ float sigm_(float x) { return 1.f / (1.f + expf(-x)); }
__device__ __forceinline__ float softplus_(float x) { return x > 20.f ? x : log1pf(expf(x)); }
__device__ __forceinline__ u16 f2bf(float f) {
    unsigned u = __float_as_uint(f);
    u += 0x7fffu + ((u >> 16) & 1u);
    return (u16)(u >> 16);
}
__device__ __forceinline__ float bf2f(u16 h) { return __uint_as_float((unsigned)h << 16); }
__device__ __forceinline__ void split2(float f, u16& h, u16& m) {
    h = f2bf(f);
    m = f2bf(f - bf2f(h));
}

__device__ __forceinline__ float wave_sum_(float v) {
#pragma unroll
    for (int o = 32; o > 0; o >>= 1) v += __shfl_down(v, o);
    return v;
}
__device__ __forceinline__ float wave_max_(float v) {
#pragma unroll
    for (int o = 32; o > 0; o >>= 1) v = fmaxf(v, __shfl_down(v, o));
    return v;
}
__device__ float block_sum_(float v, float* s) {
    int lane = threadIdx.x & 63, wid = threadIdx.x >> 6, nw = blockDim.x >> 6;
    v = wave_sum_(v);
    if (lane == 0) s[wid] = v;
    __syncthreads();
    float r = (threadIdx.x < nw) ? s[threadIdx.x] : 0.f;
    if (wid == 0) { r = wave_sum_(r); if (lane == 0) s[0] = r; }
    __syncthreads();
    float out = s[0];
    __syncthreads();
    return out;
}
__device__ float block_max_(float v, float* s) {
    int lane = threadIdx.x & 63, wid = threadIdx.x >> 6, nw = blockDim.x >> 6;
    v = wave_max_(v);
    if (lane == 0) s[wid] = v;
    __syncthreads();
    float r = (threadIdx.x < nw) ? s[threadIdx.x] : -3.4e38f;
    if (wid == 0) { r = wave_max_(r); if (lane == 0) s[0] = r; }
    __syncthreads();
    float out = s[0];
    __syncthreads();
    return out;
}

// ---------------- grid barrier: slot arrival + flag release + per-block acquire fence ----------------
// Stores are write-through sc1, so no release-side wbl2 is needed (no dirty shared lines).
// Acquire side: ONE buffer_inv per block per barrier (the fence builtin), so the phase's
// cached reads refill from the coherent MALL and then enjoy L2 hits.
__device__ __forceinline__ void gsync(unsigned* slots, unsigned* flag, unsigned epoch) {
    __syncthreads();
    if (threadIdx.x == 0)
        __hip_atomic_store(&slots[blockIdx.x * 16], epoch, __ATOMIC_RELAXED,
                           __HIP_MEMORY_SCOPE_AGENT);
    if (blockIdx.x == 0) {
        while (__hip_atomic_load(&slots[threadIdx.x * 16], __ATOMIC_RELAXED,
                                 __HIP_MEMORY_SCOPE_AGENT) < epoch)
            __builtin_amdgcn_s_sleep(1);
        while (__hip_atomic_load(&slots[(threadIdx.x + 256) * 16], __ATOMIC_RELAXED,
                                 __HIP_MEMORY_SCOPE_AGENT) < epoch)
            __builtin_amdgcn_s_sleep(1);
        __syncthreads();  // all 512 slots arrived
        if (threadIdx.x == 0)
            __hip_atomic_store(flag, epoch, __ATOMIC_RELAXED, __HIP_MEMORY_SCOPE_AGENT);
    } else if (threadIdx.x == 0) {
        while (__hip_atomic_load(flag, __ATOMIC_RELAXED, __HIP_MEMORY_SCOPE_AGENT) < epoch)
            __builtin_amdgcn_s_sleep(1);
    }
    if (threadIdx.x == 0)
        __builtin_amdgcn_fence(__ATOMIC_ACQUIRE, "agent");  // s_waitcnt + buffer_inv (no wbl2)
    __syncthreads();
}

// ---------------- epilogues (per 16x16 fragment: rows r0..r0+3 (A-rows), col c (B-row)) ----------------
struct EpiEA0 {  // prologue ea only (separate kernel launch -> plain stores OK): r=b, c=m
    const float* bea; u16* eT; u16* aT;
    __device__ void operator()(int r0, int c, v4f v) const {
#pragma unroll
        for (int r = 0; r < 4; r++) {
            float val = v[r] + bea[c];
            u16* dst;
            int b = r0 + r;
            if (c < M_) { val = sigm_(val); dst = eT + (size_t)c * B_ + b; }
            else        { val = tanhf(val); dst = aT + (size_t)(c - M_) * B_ + b; }
            u16 h, m; split2(val, h, m);
            dst[0] = h; dst[PL_H] = m;
        }
    }
};
struct EpiR {  // C[b][m] -> r planes (sc1)
    u16* rp;
    __device__ void operator()(int r0, int c, v4f v) const {
#pragma unroll
        for (int r = 0; r < 4; r++) {
            u16 h, m; split2(v[r], h, m);
            size_t idx = (size_t)(r0 + r) * M_ + c;
            sta_(rp + idx, h); sta_(rp + PL_H + idx, m);
        }
    }
};
struct EpiH {  // C[b][hdim] + xwx(in d_out layout, cached read) + bh -> tanh -> h (sc1)
    const float* xwxt; const float* bh; float* hf; u16* hp;
    __device__ void operator()(int r0, int c, v4f v) const {
#pragma unroll
        for (int r = 0; r < 4; r++) {
            int b = r0 + r;
            float val = tanhf(v[r] + xwxt[(size_t)b * (T_ * O_) + c] + bh[c]);
            size_t idx = (size_t)b * H_ + c;
            sta_(hf + idx, val);
            u16 h, m; split2(val, h, m);
            sta_(hp + idx, h); sta_(hp + PL_H + idx, m);
        }
    }
};
struct EpiFused {  // c<1024: keys; 1024..1535: out; 1536..: ea(next step) -- all sc1
    const float* bhw; const float* bhr; const float* bo; const float* bea;
    u16* khp; float* outt; u16* eT; u16* aT;
    __device__ void operator()(int r0, int c, v4f v) const {
        if (c < 1024) {
            int head = c >> 9, key = c & 511;
            const float* bb = head ? bhr : bhw;
#pragma unroll
            for (int r = 0; r < 4; r++) {
                float val = tanhf(v[r] + bb[key]);
                size_t idx = (size_t)(head * 256 + r0 + r) * M_ + key;
                u16 h, m; split2(val, h, m);
                sta_(khp + idx, h); sta_(khp + PL_KH + idx, m);
            }
        } else if (c < 1536) {
            int o = c - 1024;
#pragma unroll
            for (int r = 0; r < 4; r++)
                sta_(outt + (size_t)(r0 + r) * (T_ * O_) + o, sigm_(v[r] + bo[o]));
        } else {
            int m = c - 1536;
#pragma unroll
            for (int r = 0; r < 4; r++) {
                float val = v[r] + bea[m];
                u16* dst;
                int b = r0 + r;
                if (m < M_) { val = sigm_(val); dst = eT + (size_t)m * B_ + b; }
                else        { val = tanhf(val); dst = aT + (size_t)(m - M_) * B_ + b; }
                u16 h, mm; split2(val, h, mm);
                sta_(dst, h); sta_(dst + PL_H, mm);
            }
        }
    }
};

// ---------------- persistent-kernel args ----------------
struct NtmArgs {
    const u16 *BigT, *WxT, *WrT;
    u16 *mem_pl, *memT_pl, *wwT_pl, *wr_pl, *h_pl, *r_pl, *eT_pl, *aT_pl, *kh_pl;
    float *memf, *wwf, *wrf, *hf, *logits, *ssqp;
    const float *w6w, *w6r, *bh, *bhw, *bhr, *bea, *bo;
    float* out;
    unsigned* slots;
    unsigned* flag;
};

// ---------------- device: generic 3-product MFMA GEMM tile (TM=32 x 64, BK=32) ----------------
// All operand reads are normal cached loads (fresh after the barrier's acquire fence).
template <class Epi>
__device__ __forceinline__ void dev_gemm32(char* smc, const u16* __restrict__ Ap, int lda, int apl,
                                           const u16* __restrict__ Bp, int ldb, int bpl,
                                           int K, int row0, int col0, const Epi& epi) {
    typedef u16 (*AsT)[32][40];
    typedef u16 (*BsT)[64][40];
    AsT As = (AsT)smc;            // [2][32][40] = 5120 B
    BsT Bs = (BsT)(smc + 5120);   // [2][64][40] = 10240 B
    const int tid = threadIdx.x, lane = tid & 63, w = tid >> 6;
    const int wy = w >> 1, wx = w & 1, q = lane >> 4, l15 = lane & 15;
    uint4 ra, rb[2];
    auto loadA = [&](int k0) {
        int s = tid, p = s >> 7, rr = (s >> 2) & 31, kg = s & 3;
        ra = *(const uint4*)(Ap + (size_t)p * apl + (size_t)(row0 + rr) * lda + k0 + kg * 8);
    };
    auto loadB = [&](int k0) {
#pragma unroll
        for (int j = 0; j < 2; j++) {
            int s = j * 256 + tid, p = s >> 8, rr = (s >> 2) & 63, kg = s & 3;
            rb[j] = *(const uint4*)(Bp + (size_t)p * bpl + (size_t)(col0 + rr) * ldb + k0 + kg * 8);
        }
    };
    v4f acc[2] = {};
    loadA(0); loadB(0);
    for (int k0 = 0; k0 < K; k0 += 32) {
        {
            int s = tid, p = s >> 7, rr = (s >> 2) & 31, kg = s & 3;
            *(uint4*)&As[p][rr][kg * 8] = ra;
        }
#pragma unroll
        for (int j = 0; j < 2; j++) {
            int s = j * 256 + tid, p = s >> 8, rr = (s >> 2) & 63, kg = s & 3;
            *(uint4*)&Bs[p][rr][kg * 8] = rb[j];
        }
        __syncthreads();
        if (k0 + 32 < K) { loadA(k0 + 32); loadB(k0 + 32); }
        v8s af0 = *(const v8s*)&As[0][wy * 16 + l15][q * 8];
        v8s af1 = *(const v8s*)&As[1][wy * 16 + l15][q * 8];
        v8s bf[2][2];
#pragma unroll
        for (int nt = 0; nt < 2; nt++) {
            bf[nt][0] = *(const v8s*)&Bs[0][wx * 32 + nt * 16 + l15][q * 8];
            bf[nt][1] = *(const v8s*)&Bs[1][wx * 32 + nt * 16 + l15][q * 8];
        }
#pragma unroll
        for (int nt = 0; nt < 2; nt++) {
            v4f c = acc[nt];
            c = MFMA(af0, bf[nt][0], c);
            c = MFMA(af0, bf[nt][1], c);
            c = MFMA(af1, bf[nt][0], c);
            acc[nt] = c;
        }
        __syncthreads();
    }
#pragma unroll
    for (int nt = 0; nt < 2; nt++)
        epi(row0 + wy * 16 + q * 4, col0 + wx * 32 + nt * 16 + l15, acc[nt]);
}

// ---------------- device: memupd (Se=wwT@eT^T, Sa=wwT@aT^T; mem update; row ssq partials) ----------------
__device__ void dev_memupd(char* smc, int bid, const NtmArgs& A) {
    typedef u16 (*T64)[64][40];
    T64 As = (T64)smc;                 // 10240 B
    T64 Be = (T64)(smc + 10240);
    T64 Ba = (T64)(smc + 20480);
    float* ssqs = (float*)(smc + 30720);
    const int tid = threadIdx.x, lane = tid & 63, w = tid >> 6;
    const int wy = w >> 1, wx = w & 1, q = lane >> 4, l15 = lane & 15;
    const int bx = bid & 7, by = bid >> 3;   // bx = xcd heuristic: eT/aT slices shared per XCD
    const int row0 = by * 64, col0 = bx * 64;  // row=n, col=m
    if (tid < 64) ssqs[tid] = 0.f;
    uint4 rA[2], rE[2], rB[2];
    auto loadAll = [&](int k0) {
#pragma unroll
        for (int j = 0; j < 2; j++) {
            int s = j * 256 + tid, p = s >> 8, rr = (s >> 2) & 63, kg = s & 3;
            rA[j] = *(const uint4*)(A.wwT_pl + (size_t)p * PL_W + (size_t)(row0 + rr) * B_ + k0 + kg * 8);
            rE[j] = *(const uint4*)(A.eT_pl + (size_t)p * PL_H + (size_t)(col0 + rr) * B_ + k0 + kg * 8);
            rB[j] = *(const uint4*)(A.aT_pl + (size_t)p * PL_H + (size_t)(col0 + rr) * B_ + k0 + kg * 8);
        }
    };
    v4f ae[2][2] = {}, aa[2][2] = {};
    loadAll(0);
    for (int k0 = 0; k0 < B_; k0 += 32) {
#pragma unroll
        for (int j = 0; j < 2; j++) {
            int s = j * 256 + tid, p = s >> 8, rr = (s >> 2) & 63, kg = s & 3;
            *(uint4*)&As[p][rr][kg * 8] = rA[j];
            *(uint4*)&Be[p][rr][kg * 8] = rE[j];
            *(uint4*)&Ba[p][rr][kg * 8] = rB[j];
        }
        __syncthreads();
        if (k0 + 32 < B_) loadAll(k0 + 32);
        v8s af[2][2], be[2][2], ba[2][2];
#pragma unroll
        for (int mt = 0; mt < 2; mt++) {
            af[mt][0] = *(const v8s*)&As[0][wy * 32 + mt * 16 + l15][q * 8];
            af[mt][1] = *(const v8s*)&As[1][wy * 32 + mt * 16 + l15][q * 8];
            be[mt][0] = *(const v8s*)&Be[0][wx * 32 + mt * 16 + l15][q * 8];
            be[mt][1] = *(const v8s*)&Be[1][wx * 32 + mt * 16 + l15][q * 8];
            ba[mt][0] = *(const v8s*)&Ba[0][wx * 32 + mt * 16 + l15][q * 8];
            ba[mt][1] = *(const v8s*)&Ba[1][wx * 32 + mt * 16 + l15][q * 8];
        }
#pragma unroll
        for (int mt = 0; mt < 2; mt++)
#pragma unroll
            for (int nt = 0; nt < 2; nt++) {
                v4f c = ae[mt][nt];
                c = MFMA(af[mt][0], be[nt][0], c);
                c = MFMA(af[mt][0], be[nt][1], c);
                c = MFMA(af[mt][1], be[nt][0], c);
                ae[mt][nt] = c;
                v4f d = aa[mt][nt];
                d = MFMA(af[mt][0], ba[nt][0], d);
                d = MFMA(af[mt][0], ba[nt][1], d);
                d = MFMA(af[mt][1], ba[nt][0], d);
                aa[mt][nt] = d;
            }
        __syncthreads();
    }
    const float invB = 1.f / (float)B_;
#pragma unroll
    for (int mt = 0; mt < 2; mt++)
#pragma unroll
        for (int nt = 0; nt < 2; nt++) {
            int r0 = row0 + wy * 32 + mt * 16 + q * 4;
            int c  = col0 + wx * 32 + nt * 16 + l15;
            u16 hv[4][2];
#pragma unroll
            for (int r = 0; r < 4; r++) {
                size_t idx = (size_t)(r0 + r) * M_ + c;
                float old = A.memf[idx];  // block-owned tile, sc1-written last step, cached read
                float nv = old * (1.f - ae[mt][nt][r] * invB) + aa[mt][nt][r] * invB;
                sta_(A.memf + idx, nv);
                u16 h, m; split2(nv, h, m);
                sta_(A.mem_pl + idx, h); sta_(A.mem_pl + PL_MEM + idx, m);
                hv[r][0] = h; hv[r][1] = m;
                atomicAdd(&ssqs[r0 + r - row0], nv * nv);
            }
            size_t tb = (size_t)c * N_ + r0;
            st64_(A.memT_pl + tb, hv[0][0], hv[1][0], hv[2][0], hv[3][0]);
            st64_(A.memT_pl + PL_MEM + tb, hv[0][1], hv[1][1], hv[2][1], hv[3][1]);
        }
    __syncthreads();
    if (tid < 64) sta_(A.ssqp + (size_t)(row0 + tid) * 8 + bx, ssqs[tid]);
}

// ---------------- device: logits = (kh @ mem^T) * invn ----------------
__device__ void dev_logits(char* smc, int bx, int by, const NtmArgs& A) {
    typedef u16 (*T64)[64][40];
    T64 As = (T64)smc;
    T64 Bs = (T64)(smc + 10240);
    float* invn_s = (float*)(smc + 20480);
    const int tid = threadIdx.x, lane = tid & 63, w = tid >> 6;
    const int wy = w >> 1, wx = w & 1, q = lane >> 4, l15 = lane & 15;
    const int row0 = by * 64, col0 = bx * 64;  // row in [0,512), col=n
    if (tid < 64) {
        float s = 0.f;
#pragma unroll
        for (int j = 0; j < 8; j++) s += A.ssqp[(size_t)(col0 + tid) * 8 + j];
        invn_s[tid] = 1.f / (sqrtf(s) + EPS_);
    }
    uint4 ra[2], rb[2];
    auto loadAll = [&](int k0) {
#pragma unroll
        for (int j = 0; j < 2; j++) {
            int s = j * 256 + tid, p = s >> 8, rr = (s >> 2) & 63, kg = s & 3;
            ra[j] = *(const uint4*)(A.kh_pl + (size_t)p * PL_KH + (size_t)(row0 + rr) * M_ + k0 + kg * 8);
            rb[j] = *(const uint4*)(A.mem_pl + (size_t)p * PL_MEM + (size_t)(col0 + rr) * M_ + k0 + kg * 8);
        }
    };
    v4f acc[2][2] = {};
    loadAll(0);
    for (int k0 = 0; k0 < M_; k0 += 32) {
#pragma unroll
        for (int j = 0; j < 2; j++) {
            int s = j * 256 + tid, p = s >> 8, rr = (s >> 2) & 63, kg = s & 3;
            *(uint4*)&As[p][rr][kg * 8] = ra[j];
            *(uint4*)&Bs[p][rr][kg * 8] = rb[j];
        }
        __syncthreads();
        if (k0 + 32 < M_) loadAll(k0 + 32);
        v8s af[2][2], bf[2][2];
#pragma unroll
        for (int mt = 0; mt < 2; mt++) {
            af[mt][0] = *(const v8s*)&As[0][wy * 32 + mt * 16 + l15][q * 8];
            af[mt][1] = *(const v8s*)&As[1][wy * 32 + mt * 16 + l15][q * 8];
            bf[mt][0] = *(const v8s*)&Bs[0][wx * 32 + mt * 16 + l15][q * 8];
            bf[mt][1] = *(const v8s*)&Bs[1][wx * 32 + mt * 16 + l15][q * 8];
        }
#pragma unroll
        for (int mt = 0; mt < 2; mt++)
#pragma unroll
            for (int nt = 0; nt < 2; nt++) {
                v4f c = acc[mt][nt];
                c = MFMA(af[mt][0], bf[nt][0], c);
                c = MFMA(af[mt][0], bf[nt][1], c);
                c = MFMA(af[mt][1], bf[nt][0], c);
                acc[mt][nt] = c;
            }
        __syncthreads();
    }
#pragma unroll
    for (int mt = 0; mt < 2; mt++)
#pragma unroll
        for (int nt = 0; nt < 2; nt++) {
            int r0 = row0 + wy * 32 + mt * 16 + q * 4;
            int c  = col0 + wx * 32 + nt * 16 + l15;
            float in_ = invn_s[c - col0];
#pragma unroll
            for (int r = 0; r < 4; r++)
                sta_(A.logits + (size_t)(r0 + r) * N_ + c, acc[mt][nt][r] * in_);
        }
}

// ---------------- device: addressing tail ----------------
__device__ void dev_addr(char* smc, int row, const NtmArgs& A) {
    float* wgs = (float*)smc;           // N_ floats = 4096 B
    float* red = (float*)(smc + 4096);  // 8 floats
    int head = row >> 8, b = row & 255;
    const float* w6 = head ? A.w6r : A.w6w;
    const float* bias = head ? A.bhr : A.bhw;
    float* wf = head ? A.wrf : A.wwf;   // master row b: exclusively owned by this block
    int tid = threadIdx.x;
    float d0 = 0, d1 = 0, d2 = 0, d3 = 0, d4 = 0, d5 = 0, ssq = 0;
#pragma unroll
    for (int j = 0; j < 2; j++) {
        int k = tid + j * 256;
        float hv = A.hf[(size_t)b * H_ + k];
        const float* wk = w6 + k * 6;
        d0 += hv * wk[0]; d1 += hv * wk[1]; d2 += hv * wk[2];
        d3 += hv * wk[3]; d4 += hv * wk[4]; d5 += hv * wk[5];
        size_t ki = (size_t)row * M_ + k;
        float kv = bf2f(A.kh_pl[ki]) + bf2f(A.kh_pl[PL_KH + ki]);
        ssq += kv * kv;
    }
    d0 = block_sum_(d0, red); d1 = block_sum_(d1, red); d2 = block_sum_(d2, red);
    d3 = block_sum_(d3, red); d4 = block_sum_(d4, red); d5 = block_sum_(d5, red);
    ssq = block_sum_(ssq, red);
    float beta = softplus_(d0 + bias[M_]);
    float g = sigm_(d1 + bias[M_ + 1]);
    float a0 = d2 + bias[M_ + 2], a1 = d3 + bias[M_ + 3], a2 = d4 + bias[M_ + 4];
    float mx3 = fmaxf(a0, fmaxf(a1, a2));
    float e0 = expf(a0 - mx3), e1 = expf(a1 - mx3), e2 = expf(a2 - mx3);
    float es = e0 + e1 + e2;
    float s0 = e0 / es, s1 = e1 / es, s2 = e2 / es;
    float gamma = 1.f + softplus_(d5 + bias[M_ + 5]);
    float rowsc = beta / (sqrtf(ssq) + EPS_);
    float l[4];
#pragma unroll
    for (int j = 0; j < 4; j++) l[j] = A.logits[(size_t)row * N_ + tid * 4 + j] * rowsc;
    float mx = fmaxf(fmaxf(l[0], l[1]), fmaxf(l[2], l[3]));
    mx = block_max_(mx, red);
    float ex[4], sum = 0.f;
#pragma unroll
    for (int j = 0; j < 4; j++) { ex[j] = expf(l[j] - mx); sum += ex[j]; }
    sum = block_sum_(sum, red);
    float inv = 1.f / sum;
    float wprev[4];
#pragma unroll
    for (int j = 0; j < 4; j++) wprev[j] = wf[(size_t)b * N_ + tid * 4 + j];
#pragma unroll
    for (int j = 0; j < 4; j++) wgs[tid * 4 + j] = g * ex[j] * inv + (1.f - g) * wprev[j];
    __syncthreads();
    float wp[4], psum = 0.f;
#pragma unroll
    for (int j = 0; j < 4; j++) {
        int n = tid * 4 + j;
        float wt = s0 * wgs[(n + 1) & (N_ - 1)] + s1 * wgs[n] + s2 * wgs[(n - 1) & (N_ - 1)];
        float v = expf(gamma * logf(wt));
        wp[j] = v; psum += v;
    }
    psum = block_sum_(psum, red);
    float invp = 1.f / (psum + EPS_);
#pragma unroll
    for (int j = 0; j < 4; j++) {
        int n = tid * 4 + j;
        float val = wp[j] * invp;
        sta_(wf + (size_t)b * N_ + n, val);
        u16 h, m; split2(val, h, m);
        if (head == 0) {
            size_t tb = (size_t)n * B_ + b;
            sta_(A.wwT_pl + tb, h); sta_(A.wwT_pl + PL_W + tb, m);
        } else {
            size_t idx = (size_t)b * N_ + n;
            sta_(A.wr_pl + idx, h); sta_(A.wr_pl + PL_W + idx, m);
        }
    }
}

// ---------------- persistent kernel: the whole T-loop ----------------
__global__ __launch_bounds__(256, 2) void ntm_loop(NtmArgs A) {
    __shared__ __align__(16) char sm[31232];
    const int bid = blockIdx.x;
    unsigned ep = 0;
    for (int t = 0; t < T_; t++) {
        // 1. mem update + row-ssq partials  [n x m, K=256]  (128 tiles, bx=xcd)
        if (bid < 128) dev_memupd(sm, bid, A);
        gsync(A.slots, A.flag, ++ep);
        // 2. r = wr @ mem  [256 x 512, K=1024]  (64 tiles, bx=xcd: memT slice/XCD)
        if (bid < 64) {
            int bx = bid & 7, by = bid >> 3;
            dev_gemm32(sm, A.wr_pl, 1024, PL_W, A.memT_pl, 1024, PL_MEM, 1024,
                       by * 32, bx * 64, EpiR{A.r_pl});
        }
        gsync(A.slots, A.flag, ++ep);
        // 3. h = tanh(xwx + r @ Wr + bh)  [256 x 512, K=512]  (64 tiles, bx=xcd: WrT slice/XCD)
        if (bid < 64) {
            int bx = bid & 7, by = bid >> 3;
            dev_gemm32(sm, A.r_pl, 512, PL_H, A.WrT, 512, PL_WRT, 512,
                       by * 32, bx * 64,
                       EpiH{A.out + (size_t)t * O_, A.bh, A.hf, A.h_pl});
        }
        gsync(A.slots, A.flag, ++ep);
        // 4. fused: h @ [Whw_k | Whr_k | Wo | Wea]  (320 tiles; 5 BigT slices per XCD)
        if (bid < 320) {
            int g = bid & 7, idx = bid >> 3;           // idx 0..39
            int bx = g * 5 + idx % 5, by = idx / 5;    // bx 0..39, by 0..7
            dev_gemm32(sm, A.h_pl, 512, PL_H, A.BigT, 512, PL_BIG, 512,
                       by * 32, bx * 64,
                       EpiFused{A.bhw, A.bhr, A.bo, A.bea, A.kh_pl,
                                A.out + (size_t)t * O_, A.eT_pl, A.aT_pl});
        }
        gsync(A.slots, A.flag, ++ep);
        // 5. logits = (kh @ mem^T) * invn  [512 x 1024, K=512]  (128 tiles; 2 mem slices/XCD)
        if (bid < 128) {
            int g = bid & 7, idx = bid >> 3;           // idx 0..15
            int bx = g * 2 + (idx & 1), by = idx >> 1; // bx 0..15, by 0..7
            dev_logits(sm, bx, by, A);
        }
        gsync(A.slots, A.flag, ++ep);
        // 6. addressing tail -> ww/wr masters + planes  (512 rows, 1 per block)
        for (int row = bid; row < 2 * B_; row += NB_) dev_addr(sm, row, A);
        gsync(A.slots, A.flag, ++ep);
    }
}

// ---------------- generic 3-product MFMA GEMM (prologue use only) ----------------
template <int TM, class Epi>
__global__ __launch_bounds__(256) void gemm2(const u16* __restrict__ Ap, int lda, int apl,
                                             const u16* __restrict__ Bp, int ldb, int bpl,
                                             int K, Epi epi) {
    constexpr int AL = (TM * 32 * 2) / (256 * 8);
    constexpr int MT = TM / 32;
    __shared__ u16 As[2][TM][40];
    __shared__ u16 Bs[2][64][40];
    const int tid = threadIdx.x, lane = tid & 63, w = tid >> 6;
    const int wy = w >> 1, wx = w & 1, q = lane >> 4, l15 = lane & 15;
    const int row0 = blockIdx.y * TM, col0 = blockIdx.x * 64;
    uint4 ra[AL], rb[2];
    auto loadA = [&](int k0) {
#pragma unroll
        for (int j = 0; j < AL; j++) {
            int s = j * 256 + tid, p = s / (TM * 4), rr = (s >> 2) % TM, kg = s & 3;
            ra[j] = *(const uint4*)(Ap + (size_t)p * apl + (size_t)(row0 + rr) * lda + k0 + kg * 8);
        }
    };
    auto loadB = [&](int k0) {
#pragma unroll
        for (int j = 0; j < 2; j++) {
            int s = j * 256 + tid, p = s >> 8, rr = (s >> 2) & 63, kg = s & 3;
            rb[j] = *(const uint4*)(Bp + (size_t)p * bpl + (size_t)(col0 + rr) * ldb + k0 + kg * 8);
        }
    };
    v4f acc[MT][2] = {};
    loadA(0); loadB(0);
    for (int k0 = 0; k0 < K; k0 += 32) {
#pragma unroll
        for (int j = 0; j < AL; j++) {
            int s = j * 256 + tid, p = s / (TM * 4), rr = (s >> 2) % TM, kg = s & 3;
            *(uint4*)&As[p][rr][kg * 8] = ra[j];
        }
#pragma unroll
        for (int j = 0; j < 2; j++) {
            int s = j * 256 + tid, p = s >> 8, rr = (s >> 2) & 63, kg = s & 3;
            *(uint4*)&Bs[p][rr][kg * 8] = rb[j];
        }
        __syncthreads();
        if (k0 + 32 < K) { loadA(k0 + 32); loadB(k0 + 32); }
        v8s af[MT][2], bf[2][2];
#pragma unroll
        for (int mt = 0; mt < MT; mt++) {
            af[mt][0] = *(const v8s*)&As[0][wy * (TM / 2) + mt * 16 + l15][q * 8];
            af[mt][1] = *(const v8s*)&As[1][wy * (TM / 2) + mt * 16 + l15][q * 8];
        }
#pragma unroll
        for (int nt = 0; nt < 2; nt++) {
            bf[nt][0] = *(const v8s*)&Bs[0][wx * 32 + nt * 16 + l15][q * 8];
            bf[nt][1] = *(const v8s*)&Bs[1][wx * 32 + nt * 16 + l15][q * 8];
        }
#pragma unroll
        for (int mt = 0; mt < MT; mt++)
#pragma unroll
            for (int nt = 0; nt < 2; nt++) {
                v4f c = acc[mt][nt];
                c = MFMA(af[mt][0], bf[nt][0], c);
                c = MFMA(af[mt][0], bf[nt][1], c);
                c = MFMA(af[mt][1], bf[nt][0], c);
                acc[mt][nt] = c;
            }
        __syncthreads();
    }
#pragma unroll
    for (int mt = 0; mt < MT; mt++)
#pragma unroll
        for (int nt = 0; nt < 2; nt++)
            epi(row0 + wy * (TM / 2) + mt * 16 + q * 4, col0 + wx * 32 + nt * 16 + l15, acc[mt][nt]);
}

// ---------------- xwx GEMM: rows (t*256+b), A split from f32 on the fly, out -> d_out[b][t][:] ----------------
__global__ __launch_bounds__(256) void gemm2_xwx(const float* __restrict__ x, const u16* __restrict__ WxT,
                                                 float* __restrict__ outbuf) {
    __shared__ u16 As[2][64][40];
    __shared__ u16 Bs[2][64][40];
    const int tid = threadIdx.x, lane = tid & 63, w = tid >> 6;
    const int wy = w >> 1, wx = w & 1, q = lane >> 4, l15 = lane & 15;
    const int row0 = blockIdx.y * 64, col0 = blockIdx.x * 64;
    const int sr = tid >> 2, ss = (tid & 3) * 8;
    const int arow = row0 + sr, ab = arow & 255, at = arow >> 8;
    const float* Asrc = x + ((size_t)ab * T_ + at) * I_ + ss;
    v4f acc[2][2] = {};
    for (int k0 = 0; k0 < I_; k0 += 32) {
        float4 f0 = *(const float4*)(Asrc + k0);
        float4 f1 = *(const float4*)(Asrc + k0 + 4);
        float av8[8] = {f0.x, f0.y, f0.z, f0.w, f1.x, f1.y, f1.z, f1.w};
#pragma unroll
        for (int j = 0; j < 8; j++) {
            u16 h, m; split2(av8[j], h, m);
            As[0][sr][ss + j] = h; As[1][sr][ss + j] = m;
        }
#pragma unroll
        for (int p = 0; p < 2; p++)
            *(uint4*)&Bs[p][sr][ss] = *(const uint4*)&WxT[(size_t)p * PL_WXT + (size_t)(col0 + sr) * I_ + k0 + ss];
        __syncthreads();
        v8s af[2][2], bf[2][2];
#pragma unroll
        for (int mt = 0; mt < 2; mt++) {
            af[mt][0] = *(const v8s*)&As[0][wy * 32 + mt * 16 + l15][q * 8];
            af[mt][1] = *(const v8s*)&As[1][wy * 32 + mt * 16 + l15][q * 8];
            bf[mt][0] = *(const v8s*)&Bs[0][wx * 32 + mt * 16 + l15][q * 8];
            bf[mt][1] = *(const v8s*)&Bs[1][wx * 32 + mt * 16 + l15][q * 8];
        }
#pragma unroll
        for (int mt = 0; mt < 2; mt++)
#pragma unroll
            for (int nt = 0; nt < 2; nt++) {
                v4f c = acc[mt][nt];
                c = MFMA(af[mt][0], bf[nt][0], c);
                c = MFMA(af[mt][0], bf[nt][1], c);
                c = MFMA(af[mt][1], bf[nt][0], c);
                acc[mt][nt] = c;
            }
        __syncthreads();
    }
#pragma unroll
    for (int mt = 0; mt < 2; mt++)
#pragma unroll
        for (int nt = 0; nt < 2; nt++) {
            int r0 = row0 + wy * 32 + mt * 16 + q * 4;
            int c  = col0 + wx * 32 + nt * 16 + l15;
#pragma unroll
            for (int r = 0; r < 4; r++) {
                int row = r0 + r, b = row & 255, t = row >> 8;
                outbuf[((size_t)b * T_ + t) * O_ + c] = acc[mt][nt][r];
            }
        }
}

// ---------------- decomp: transpose + split2: in f32 [R][ldin] cols c0.. -> planes [C][R] ----------------
__global__ __launch_bounds__(256) void decomp_t(const float* __restrict__ in, int ldin, int c0,
                                                int R, u16* __restrict__ outp, int opl) {
    __shared__ float Ls[32][33];
    const int r0 = blockIdx.x * 32, cB = blockIdx.y * 32;
    const int tid = threadIdx.x;
    int lr = tid >> 3, lc = (tid & 7) * 4;
#pragma unroll
    for (int j = 0; j < 4; j++)
        Ls[lr][lc + j] = in[(size_t)(r0 + lr) * ldin + c0 + cB + lc + j];
    __syncthreads();
    int lc2 = tid >> 3, lr2 = (tid & 7) * 4;
    u16 hv[4], mv[4];
#pragma unroll
    for (int j = 0; j < 4; j++) split2(Ls[lr2 + j][lc2], hv[j], mv[j]);
    size_t base = (size_t)(cB + lc2) * R + r0 + lr2;
    *(ushort4*)&outp[0 * (size_t)opl + base] = make_ushort4(hv[0], hv[1], hv[2], hv[3]);
    *(ushort4*)&outp[1 * (size_t)opl + base] = make_ushort4(mv[0], mv[1], mv[2], mv[3]);
}

// ---------------- init / misc ----------------
__global__ __launch_bounds__(512) void wh6_kernel(const float* __restrict__ Whw, const float* __restrict__ Whr,
                                                  float* __restrict__ w6w, float* __restrict__ w6r,
                                                  unsigned* __restrict__ barz) {
    int k = threadIdx.x;
    if (blockIdx.x == 0) {
        for (int i = k; i < NB_ * 16 + 16; i += 512) barz[i] = 0u;  // 512 slots*16 + flag line
    }
    const float* src = blockIdx.x ? Whr : Whw;
    float* dst = blockIdx.x ? w6r : w6w;
#pragma unroll
    for (int j = 0; j < 6; j++) dst[k * 6 + j] = src[(size_t)k * (M_ + 6) + M_ + j];
}
__global__ __launch_bounds__(256) void init_mem(const float* __restrict__ mem0, float* __restrict__ memf,
                                                u16* __restrict__ mem_pl, u16* __restrict__ memT_pl) {
    int n = blockIdx.x;
    for (int c = threadIdx.x; c < M_; c += 256) {
        float v = mem0[(size_t)n * M_ + c];
        size_t idx = (size_t)n * M_ + c;
        memf[idx] = v;
        u16 h, m; split2(v, h, m);
        mem_pl[idx] = h; mem_pl[PL_MEM + idx] = m;
        size_t tb = (size_t)c * N_ + n;
        memT_pl[tb] = h; memT_pl[PL_MEM + tb] = m;
    }
}
__global__ __launch_bounds__(256) void init_w(const float* __restrict__ wr0, const float* __restrict__ ww0,
                                              float* __restrict__ wrf, float* __restrict__ wwf,
                                              u16* __restrict__ wr_pl, u16* __restrict__ wwT_pl) {
    int b = blockIdx.x;
    for (int n = threadIdx.x; n < N_; n += 256) {
        size_t idx = (size_t)b * N_ + n;
        float vw = ww0[idx]; wwf[idx] = vw;
        u16 h, m; split2(vw, h, m);
        size_t tb = (size_t)n * B_ + b;
        wwT_pl[tb] = h; wwT_pl[PL_W + tb] = m;
        float vr = wr0[idx]; wrf[idx] = vr;
        split2(vr, h, m);
        wr_pl[idx] = h; wr_pl[PL_W + idx] = m;
    }
}
__global__ __launch_bounds__(64) void init_h(const float* __restrict__ h0, float* __restrict__ hf,
                                             u16* __restrict__ hp) {
    int b = blockIdx.x;
    for (int c = threadIdx.x; c < H_; c += 64) {
        size_t idx = (size_t)b * H_ + c;
        float v = h0[idx];
        hf[idx] = v;
        u16 h, m; split2(v, h, m);
        hp[idx] = h; hp[PL_H + idx] = m;
    }
}

// ---------------- host ----------------
extern "C" void kernel_launch(void* const* d_in, const int* in_sizes, int n_in,
                              void* d_out, int out_size, void* d_ws, size_t ws_size,
                              hipStream_t stream) {
    (void)in_sizes; (void)n_in; (void)out_size; (void)ws_size;
    const float* x    = (const float*)d_in[0];
    const float* mem0 = (const float*)d_in[1];
    const float* wr0  = (const float*)d_in[2];
    const float* ww0  = (const float*)d_in[3];
    const float* h0   = (const float*)d_in[4];
    const float* Wx   = (const float*)d_in[5];
    const float* Wr   = (const float*)d_in[6];
    const float* bh   = (const float*)d_in[7];
    const float* Whr  = (const float*)d_in[8];
    const float* bhr  = (const float*)d_in[9];
    const float* Whw  = (const float*)d_in[10];
    const float* bhw  = (const float*)d_in[11];
    const float* Wea  = (const float*)d_in[12];
    const float* bea  = (const float*)d_in[13];
    const float* Wo   = (const float*)d_in[14];
    const float* bo   = (const float*)d_in[15];
    float* out = (float*)d_out;

    char* wsb = (char*)d_ws;
    size_t off = 0;
    auto carveU = [&](size_t elems) { u16* p = (u16*)(wsb + off); off += elems * sizeof(u16); return p; };
    u16* BigT    = carveU(2 * (size_t)PL_BIG);
    u16* WxT     = carveU(2 * (size_t)PL_WXT);
    u16* WrT     = carveU(2 * (size_t)PL_WRT);
    u16* mem_pl  = carveU(2 * (size_t)PL_MEM);
    u16* memT_pl = carveU(2 * (size_t)PL_MEM);
    u16* wwT_pl  = carveU(2 * (size_t)PL_W);
    u16* wr_pl   = carveU(2 * (size_t)PL_W);
    u16* h_pl    = carveU(2 * (size_t)PL_H);
    u16* r_pl    = carveU(2 * (size_t)PL_H);
    u16* eT_pl   = carveU(2 * (size_t)PL_H);
    u16* aT_pl   = carveU(2 * (size_t)PL_H);
    u16* kh_pl   = carveU(2 * (size_t)PL_KH);
    auto carveF = [&](size_t elems) { float* p = (float*)(wsb + off); off += elems * sizeof(float); return p; };
    float* memf   = carveF((size_t)N_ * M_);
    float* wwf    = carveF((size_t)B_ * N_);
    float* wrf    = carveF((size_t)B_ * N_);
    float* hf     = carveF((size_t)B_ * H_);
    float* logits = carveF((size_t)2 * B_ * N_);
    float* ssqp   = carveF((size_t)N_ * 8);
    float* w6w    = carveF(H_ * 6);
    float* w6r    = carveF(H_ * 6);
    // barrier region: NB_ slots (64B apart) + flag on its own line
    off = (off + 127) & ~(size_t)127;
    unsigned* slots = (unsigned*)(wsb + off);           // slots[NB_*16]
    unsigned* flag  = slots + NB_ * 16;                 // 64B-aligned
    off += (NB_ * 16 + 16) * sizeof(unsigned) + 64;

    // ---- prologue: weight decomposition + state init (also zeroes the barrier region) ----
    decomp_t<<<dim3(16, 16), 256, 0, stream>>>(Whw, M_ + 6, 0, 512, BigT, PL_BIG);                       // rows 0-511
    decomp_t<<<dim3(16, 16), 256, 0, stream>>>(Whr, M_ + 6, 0, 512, BigT + (size_t)512 * 512, PL_BIG);   // rows 512-1023
    decomp_t<<<dim3(16, 16), 256, 0, stream>>>(Wo, 512, 0, 512, BigT + (size_t)1024 * 512, PL_BIG);      // rows 1024-1535
    decomp_t<<<dim3(16, 32), 256, 0, stream>>>(Wea, 1024, 0, 512, BigT + (size_t)1536 * 512, PL_BIG);    // rows 1536-2559
    decomp_t<<<dim3(16, 16), 256, 0, stream>>>(Wx, 512, 0, 512, WxT, PL_WXT);
    decomp_t<<<dim3(16, 16), 256, 0, stream>>>(Wr, 512, 0, 512, WrT, PL_WRT);
    wh6_kernel<<<2, 512, 0, stream>>>(Whw, Whr, w6w, w6r, slots);
    init_mem<<<N_, 256, 0, stream>>>(mem0, memf, mem_pl, memT_pl);
    init_w<<<B_, 256, 0, stream>>>(wr0, ww0, wrf, wwf, wr_pl, wwT_pl);
    init_h<<<B_, 64, 0, stream>>>(h0, hf, h_pl);
    // xwx for all (t,b) -> stored in d_out slots [b][t][:]
    gemm2_xwx<<<dim3(8, 512), 256, 0, stream>>>(x, WxT, out);
    // ea for step 0 from h0
    gemm2<32, EpiEA0><<<dim3(16, 8), 256, 0, stream>>>(
        h_pl, 512, PL_H, BigT + (size_t)1536 * 512, 512, PL_BIG, 512, EpiEA0{bea, eT_pl, aT_pl});

    // ---- the entire T-loop: one persistent kernel, sc1-stores + cached-reads + acquire fences ----
    NtmArgs A;
    A.BigT = BigT; A.WxT = WxT; A.WrT = WrT;
    A.mem_pl = mem_pl; A.memT_pl = memT_pl; A.wwT_pl = wwT_pl; A.wr_pl = wr_pl;
    A.h_pl = h_pl; A.r_pl = r_pl; A.eT_pl = eT_pl; A.aT_pl = aT_pl; A.kh_pl = kh_pl;
    A.memf = memf; A.wwf = wwf; A.wrf = wrf; A.hf = hf; A.logits = logits; A.ssqp = ssqp;
    A.w6w = w6w; A.w6r = w6r; A.bh = bh; A.bhw = bhw; A.bhr = bhr; A.bea = bea; A.bo = bo;
    A.out = out;
    A.slots = slots;
    A.flag = flag;
    ntm_loop<<<dim3(NB_), dim3(256), 0, stream>>>(A);
}

// Round 7
// 17157.167 us; speedup vs baseline: 1.6137x; 1.6137x over previous
//
#include <hip/hip_runtime.h>
#include <math.h>

// NTM recurrence. GEMMs via 3-product 2-plane bf16-split MFMA (~2^-17 rel err per GEMM,
// fp32 state masters). T-loop inside ONE persistent kernel (512 blocks, 2/CU co-resident).
// Coherence (r7 = r4 scheme, widened): NO cache fences anywhere. Mutable cross-block data
// moves via relaxed agent-scope (sc1) accesses -- loads as 8-byte dwordx2 (r4 used 4B dwords,
// 387 GB/s eff), stores write-through. Read-only weights use normal cached loads and stay
// L2-resident for all 128 steps (nothing ever invalidates L2). Phases 2/3 use 64x64 tiles
// (halved sc1 operand duplication vs 32x64).
// B=256 T=128 I=512 H=512 N=1024 M=512 O=512
#define B_ 256
#define T_ 128
#define I_ 512
#define H_ 512
#define N_ 1024
#define M_ 512
#define O_ 512
#define EPS_ 1e-8f
#define NB_ 512  // persistent grid: 512 blocks x 256 thr, 2 blocks/CU co-resident

typedef unsigned short u16;
typedef unsigned long long u64;
typedef __attribute__((ext_vector_type(8))) short v8s;   // 8 bf16 = 4 VGPRs
typedef __attribute__((ext_vector_type(4))) float v4f;   // MFMA acc

#define MFMA(a, b, c) __builtin_amdgcn_mfma_f32_16x16x32_bf16(a, b, c, 0, 0, 0)

// plane strides (elements)
#define PL_BIG 1310720  // BigT [2560][512]: rows 0-511 Whw_k, 512-1023 Whr_k, 1024-1535 Wo, 1536-2559 Wea
#define PL_WXT 262144   // WxT  [512][512]
#define PL_WRT 262144   // WrT  [512][512]
#define PL_MEM 524288   // mem  [1024][512] / memT [512][1024]
#define PL_W   262144   // wwT [1024][256] / wr [256][1024]
#define PL_H   131072   // h [256][512], r [256][512], eT/aT [512][256]
#define PL_KH  262144   // kh [512][512]

// ---------------- sc1 (agent-coherent) access helpers ----------------
template <typename T>
__device__ __forceinline__ T lda_(const T* p) {
    return __hip_atomic_load(const_cast<T*>(p), __ATOMIC_RELAXED, __HIP_MEMORY_SCOPE_AGENT);
}
template <typename T>
__device__ __forceinline__ void sta_(T* p, T v) {
    __hip_atomic_store(p, v, __ATOMIC_RELAXED, __HIP_MEMORY_SCOPE_AGENT);
}
__device__ __forceinline__ uint4 ld16_(const u16* p) {  // 16B as 2 x dwordx2 sc1
    const u64* q = (const u64*)p;
    u64 lo = __hip_atomic_load(const_cast<u64*>(q), __ATOMIC_RELAXED, __HIP_MEMORY_SCOPE_AGENT);
    u64 hi = __hip_atomic_load(const_cast<u64*>(q + 1), __ATOMIC_RELAXED, __HIP_MEMORY_SCOPE_AGENT);
    uint4 r;
    r.x = (unsigned)lo; r.y = (unsigned)(lo >> 32);
    r.z = (unsigned)hi; r.w = (unsigned)(hi >> 32);
    return r;
}
__device__ __forceinline__ void st64_(u16* p, u16 a, u16 b, u16 c, u16 d) {
    u64 v = (u64)a | ((u64)b << 16) | ((u64)c << 32) | ((u64)d << 48);
    __hip_atomic_store((u64*)p, v, __ATOMIC_RELAXED, __HIP_MEMORY_SCOPE_AGENT);
}

// ---------------- scalar helpers ----------------
__device__ __forceinline__ float sigm_(float x) { return 1.f / (1.f + expf(-x)); }
__device__ __forceinline__ float softplus_(float x) { return x > 20.f ? x : log1pf(expf(x)); }
__device__ __forceinline__ u16 f2bf(float f) {
    unsigned u = __float_as_uint(f);
    u += 0x7fffu + ((u >> 16) & 1u);
    return (u16)(u >> 16);
}
__device__ __forceinline__ float bf2f(u16 h) { return __uint_as_float((unsigned)h << 16); }
__device__ __forceinline__ void split2(float f, u16& h, u16& m) {
    h = f2bf(f);
    m = f2bf(f - bf2f(h));
}

__device__ __forceinline__ float wave_sum_(float v) {
#pragma unroll
    for (int o = 32; o > 0; o >>= 1) v += __shfl_down(v, o);
    return v;
}
__device__ __forceinline__ float wave_max_(float v) {
#pragma unroll
    for (int o = 32; o > 0; o >>= 1) v = fmaxf(v, __shfl_down(v, o));
    return v;
}
__device__ float block_sum_(float v, float* s) {
    int lane = threadIdx.x & 63, wid = threadIdx.x >> 6, nw = blockDim.x >> 6;
    v = wave_sum_(v);
    if (lane == 0) s[wid] = v;
    __syncthreads();
    float r = (threadIdx.x < nw) ? s[threadIdx.x] : 0.f;
    if (wid == 0) { r = wave_sum_(r); if (lane == 0) s[0] = r; }
    __syncthreads();
    float out = s[0];
    __syncthreads();
    return out;
}
__device__ float block_max_(float v, float* s) {
    int lane = threadIdx.x & 63, wid = threadIdx.x >> 6, nw = blockDim.x >> 6;
    v = wave_max_(v);
    if (lane == 0) s[wid] = v;
    __syncthreads();
    float r = (threadIdx.x < nw) ? s[threadIdx.x] : -3.4e38f;
    if (wid == 0) { r = wave_max_(r); if (lane == 0) s[0] = r; }
    __syncthreads();
    float out = s[0];
    __syncthreads();
    return out;
}

// ---------------- grid barrier: per-block slots + release flag, NO fences (r4) ----------------
__device__ __forceinline__ void gsync(unsigned* slots, unsigned* flag, unsigned epoch) {
    __syncthreads();
    if (threadIdx.x == 0)
        __hip_atomic_store(&slots[blockIdx.x * 16], epoch, __ATOMIC_RELAXED,
                           __HIP_MEMORY_SCOPE_AGENT);
    if (blockIdx.x == 0) {
        while (__hip_atomic_load(&slots[threadIdx.x * 16], __ATOMIC_RELAXED,
                                 __HIP_MEMORY_SCOPE_AGENT) < epoch)
            __builtin_amdgcn_s_sleep(1);
        while (__hip_atomic_load(&slots[(threadIdx.x + 256) * 16], __ATOMIC_RELAXED,
                                 __HIP_MEMORY_SCOPE_AGENT) < epoch)
            __builtin_amdgcn_s_sleep(1);
        __syncthreads();  // all 512 slots arrived
        if (threadIdx.x == 0)
            __hip_atomic_store(flag, epoch, __ATOMIC_RELAXED, __HIP_MEMORY_SCOPE_AGENT);
    } else if (threadIdx.x == 0) {
        while (__hip_atomic_load(flag, __ATOMIC_RELAXED, __HIP_MEMORY_SCOPE_AGENT) < epoch)
            __builtin_amdgcn_s_sleep(1);
    }
    __syncthreads();
}

// ---------------- epilogues (per 16x16 fragment: rows r0..r0+3 (A-rows), col c (B-row)) ----------------
struct EpiEA0 {  // prologue ea only (separate kernel launch -> plain stores OK): r=b, c=m
    const float* bea; u16* eT; u16* aT;
    __device__ void operator()(int r0, int c, v4f v) const {
#pragma unroll
        for (int r = 0; r < 4; r++) {
            float val = v[r] + bea[c];
            u16* dst;
            int b = r0 + r;
            if (c < M_) { val = sigm_(val); dst = eT + (size_t)c * B_ + b; }
            else        { val = tanhf(val); dst = aT + (size_t)(c - M_) * B_ + b; }
            u16 h, m; split2(val, h, m);
            dst[0] = h; dst[PL_H] = m;
        }
    }
};
struct EpiR {  // C[b][m] -> r planes (sc1)
    u16* rp;
    __device__ void operator()(int r0, int c, v4f v) const {
#pragma unroll
        for (int r = 0; r < 4; r++) {
            u16 h, m; split2(v[r], h, m);
            size_t idx = (size_t)(r0 + r) * M_ + c;
            sta_(rp + idx, h); sta_(rp + PL_H + idx, m);
        }
    }
};
struct EpiH {  // C[b][hdim] + xwx(in d_out layout, cached read) + bh -> tanh -> h (sc1)
    const float* xwxt; const float* bh; float* hf; u16* hp;
    __device__ void operator()(int r0, int c, v4f v) const {
#pragma unroll
        for (int r = 0; r < 4; r++) {
            int b = r0 + r;
            float val = tanhf(v[r] + xwxt[(size_t)b * (T_ * O_) + c] + bh[c]);
            size_t idx = (size_t)b * H_ + c;
            sta_(hf + idx, val);
            u16 h, m; split2(val, h, m);
            sta_(hp + idx, h); sta_(hp + PL_H + idx, m);
        }
    }
};
struct EpiFused {  // c<1024: keys; 1024..1535: out; 1536..: ea(next step)
    const float* bhw; const float* bhr; const float* bo; const float* bea;
    u16* khp; float* outt; u16* eT; u16* aT;
    __device__ void operator()(int r0, int c, v4f v) const {
        if (c < 1024) {
            int head = c >> 9, key = c & 511;
            const float* bb = head ? bhr : bhw;
#pragma unroll
            for (int r = 0; r < 4; r++) {
                float val = tanhf(v[r] + bb[key]);
                size_t idx = (size_t)(head * 256 + r0 + r) * M_ + key;
                u16 h, m; split2(val, h, m);
                sta_(khp + idx, h); sta_(khp + PL_KH + idx, m);
            }
        } else if (c < 1536) {
            int o = c - 1024;
#pragma unroll
            for (int r = 0; r < 4; r++)
                outt[(size_t)(r0 + r) * (T_ * O_) + o] = sigm_(v[r] + bo[o]);  // host-read only
        } else {
            int m = c - 1536;
#pragma unroll
            for (int r = 0; r < 4; r++) {
                float val = v[r] + bea[m];
                u16* dst;
                int b = r0 + r;
                if (m < M_) { val = sigm_(val); dst = eT + (size_t)m * B_ + b; }
                else        { val = tanhf(val); dst = aT + (size_t)(m - M_) * B_ + b; }
                u16 h, mm; split2(val, h, mm);
                sta_(dst, h); sta_(dst + PL_H, mm);
            }
        }
    }
};

// ---------------- persistent-kernel args ----------------
struct NtmArgs {
    const u16 *BigT, *WxT, *WrT;
    u16 *mem_pl, *memT_pl, *wwT_pl, *wr_pl, *h_pl, *r_pl, *eT_pl, *aT_pl, *kh_pl;
    float *memf, *wwf, *wrf, *hf, *logits, *ssqp;
    const float *w6w, *w6r, *bh, *bhw, *bhr, *bea, *bo;
    float* out;
    unsigned* slots;
    unsigned* flag;
};

// ---------------- device: 3-product MFMA GEMM tile 32x64, BK=32 (phase 4) ----------------
// AS/BS: operand via sc1 8B loads (mutable) vs normal cached (read-only weight).
template <bool AS, bool BS, class Epi>
__device__ __forceinline__ void dev_gemm32(char* smc, const u16* __restrict__ Ap, int lda, int apl,
                                           const u16* __restrict__ Bp, int ldb, int bpl,
                                           int K, int row0, int col0, const Epi& epi) {
    typedef u16 (*AsT)[32][40];
    typedef u16 (*BsT)[64][40];
    AsT As = (AsT)smc;            // [2][32][40] = 5120 B
    BsT Bs = (BsT)(smc + 5120);   // [2][64][40] = 10240 B
    const int tid = threadIdx.x, lane = tid & 63, w = tid >> 6;
    const int wy = w >> 1, wx = w & 1, q = lane >> 4, l15 = lane & 15;
    uint4 ra, rb[2];
    auto loadA = [&](int k0) {
        int s = tid, p = s >> 7, rr = (s >> 2) & 31, kg = s & 3;
        const u16* ap = Ap + (size_t)p * apl + (size_t)(row0 + rr) * lda + k0 + kg * 8;
        ra = AS ? ld16_(ap) : *(const uint4*)ap;
    };
    auto loadB = [&](int k0) {
#pragma unroll
        for (int j = 0; j < 2; j++) {
            int s = j * 256 + tid, p = s >> 8, rr = (s >> 2) & 63, kg = s & 3;
            const u16* bp = Bp + (size_t)p * bpl + (size_t)(col0 + rr) * ldb + k0 + kg * 8;
            rb[j] = BS ? ld16_(bp) : *(const uint4*)bp;
        }
    };
    v4f acc[2] = {};
    loadA(0); loadB(0);
    for (int k0 = 0; k0 < K; k0 += 32) {
        {
            int s = tid, p = s >> 7, rr = (s >> 2) & 31, kg = s & 3;
            *(uint4*)&As[p][rr][kg * 8] = ra;
        }
#pragma unroll
        for (int j = 0; j < 2; j++) {
            int s = j * 256 + tid, p = s >> 8, rr = (s >> 2) & 63, kg = s & 3;
            *(uint4*)&Bs[p][rr][kg * 8] = rb[j];
        }
        __syncthreads();
        if (k0 + 32 < K) { loadA(k0 + 32); loadB(k0 + 32); }
        v8s af0 = *(const v8s*)&As[0][wy * 16 + l15][q * 8];
        v8s af1 = *(const v8s*)&As[1][wy * 16 + l15][q * 8];
        v8s bf[2][2];
#pragma unroll
        for (int nt = 0; nt < 2; nt++) {
            bf[nt][0] = *(const v8s*)&Bs[0][wx * 32 + nt * 16 + l15][q * 8];
            bf[nt][1] = *(const v8s*)&Bs[1][wx * 32 + nt * 16 + l15][q * 8];
        }
#pragma unroll
        for (int nt = 0; nt < 2; nt++) {
            v4f c = acc[nt];
            c = MFMA(af0, bf[nt][0], c);
            c = MFMA(af0, bf[nt][1], c);
            c = MFMA(af1, bf[nt][0], c);
            acc[nt] = c;
        }
        __syncthreads();
    }
#pragma unroll
    for (int nt = 0; nt < 2; nt++)
        epi(row0 + wy * 16 + q * 4, col0 + wx * 32 + nt * 16 + l15, acc[nt]);
}

// ---------------- device: 3-product MFMA GEMM tile 64x64, BK=32 (phases 2,3) ----------------
template <bool AS, bool BS, class Epi>
__device__ __forceinline__ void dev_gemm64(char* smc, const u16* __restrict__ Ap, int lda, int apl,
                                           const u16* __restrict__ Bp, int ldb, int bpl,
                                           int K, int row0, int col0, const Epi& epi) {
    typedef u16 (*T64)[64][40];
    T64 As = (T64)smc;            // 10240 B
    T64 Bs = (T64)(smc + 10240);  // 10240 B
    const int tid = threadIdx.x, lane = tid & 63, w = tid >> 6;
    const int wy = w >> 1, wx = w & 1, q = lane >> 4, l15 = lane & 15;
    uint4 ra[2], rb[2];
    auto loadAll = [&](int k0) {
#pragma unroll
        for (int j = 0; j < 2; j++) {
            int s = j * 256 + tid, p = s >> 8, rr = (s >> 2) & 63, kg = s & 3;
            const u16* ap = Ap + (size_t)p * apl + (size_t)(row0 + rr) * lda + k0 + kg * 8;
            const u16* bp = Bp + (size_t)p * bpl + (size_t)(col0 + rr) * ldb + k0 + kg * 8;
            ra[j] = AS ? ld16_(ap) : *(const uint4*)ap;
            rb[j] = BS ? ld16_(bp) : *(const uint4*)bp;
        }
    };
    v4f acc[2][2] = {};
    loadAll(0);
    for (int k0 = 0; k0 < K; k0 += 32) {
#pragma unroll
        for (int j = 0; j < 2; j++) {
            int s = j * 256 + tid, p = s >> 8, rr = (s >> 2) & 63, kg = s & 3;
            *(uint4*)&As[p][rr][kg * 8] = ra[j];
            *(uint4*)&Bs[p][rr][kg * 8] = rb[j];
        }
        __syncthreads();
        if (k0 + 32 < K) loadAll(k0 + 32);
        v8s af[2][2], bf[2][2];
#pragma unroll
        for (int mt = 0; mt < 2; mt++) {
            af[mt][0] = *(const v8s*)&As[0][wy * 32 + mt * 16 + l15][q * 8];
            af[mt][1] = *(const v8s*)&As[1][wy * 32 + mt * 16 + l15][q * 8];
            bf[mt][0] = *(const v8s*)&Bs[0][wx * 32 + mt * 16 + l15][q * 8];
            bf[mt][1] = *(const v8s*)&Bs[1][wx * 32 + mt * 16 + l15][q * 8];
        }
#pragma unroll
        for (int mt = 0; mt < 2; mt++)
#pragma unroll
            for (int nt = 0; nt < 2; nt++) {
                v4f c = acc[mt][nt];
                c = MFMA(af[mt][0], bf[nt][0], c);
                c = MFMA(af[mt][0], bf[nt][1], c);
                c = MFMA(af[mt][1], bf[nt][0], c);
                acc[mt][nt] = c;
            }
        __syncthreads();
    }
#pragma unroll
    for (int mt = 0; mt < 2; mt++)
#pragma unroll
        for (int nt = 0; nt < 2; nt++)
            epi(row0 + wy * 32 + mt * 16 + q * 4, col0 + wx * 32 + nt * 16 + l15, acc[mt][nt]);
}

// ---------------- device: memupd (Se=wwT@eT^T, Sa=wwT@aT^T; mem update; row ssq partials) ----------------
__device__ void dev_memupd(char* smc, int bid, const NtmArgs& A) {
    typedef u16 (*T64)[64][40];
    T64 As = (T64)smc;                 // 10240 B
    T64 Be = (T64)(smc + 10240);
    T64 Ba = (T64)(smc + 20480);
    float* ssqs = (float*)(smc + 30720);
    const int tid = threadIdx.x, lane = tid & 63, w = tid >> 6;
    const int wy = w >> 1, wx = w & 1, q = lane >> 4, l15 = lane & 15;
    const int bx = bid & 7, by = bid >> 3;
    const int row0 = by * 64, col0 = bx * 64;  // row=n, col=m
    if (tid < 64) ssqs[tid] = 0.f;
    uint4 rA[2], rE[2], rB[2];
    auto loadAll = [&](int k0) {
#pragma unroll
        for (int j = 0; j < 2; j++) {
            int s = j * 256 + tid, p = s >> 8, rr = (s >> 2) & 63, kg = s & 3;
            rA[j] = ld16_(A.wwT_pl + (size_t)p * PL_W + (size_t)(row0 + rr) * B_ + k0 + kg * 8);
            rE[j] = ld16_(A.eT_pl + (size_t)p * PL_H + (size_t)(col0 + rr) * B_ + k0 + kg * 8);
            rB[j] = ld16_(A.aT_pl + (size_t)p * PL_H + (size_t)(col0 + rr) * B_ + k0 + kg * 8);
        }
    };
    v4f ae[2][2] = {}, aa[2][2] = {};
    loadAll(0);
    for (int k0 = 0; k0 < B_; k0 += 32) {
#pragma unroll
        for (int j = 0; j < 2; j++) {
            int s = j * 256 + tid, p = s >> 8, rr = (s >> 2) & 63, kg = s & 3;
            *(uint4*)&As[p][rr][kg * 8] = rA[j];
            *(uint4*)&Be[p][rr][kg * 8] = rE[j];
            *(uint4*)&Ba[p][rr][kg * 8] = rB[j];
        }
        __syncthreads();
        if (k0 + 32 < B_) loadAll(k0 + 32);
        v8s af[2][2], be[2][2], ba[2][2];
#pragma unroll
        for (int mt = 0; mt < 2; mt++) {
            af[mt][0] = *(const v8s*)&As[0][wy * 32 + mt * 16 + l15][q * 8];
            af[mt][1] = *(const v8s*)&As[1][wy * 32 + mt * 16 + l15][q * 8];
            be[mt][0] = *(const v8s*)&Be[0][wx * 32 + mt * 16 + l15][q * 8];
            be[mt][1] = *(const v8s*)&Be[1][wx * 32 + mt * 16 + l15][q * 8];
            ba[mt][0] = *(const v8s*)&Ba[0][wx * 32 + mt * 16 + l15][q * 8];
            ba[mt][1] = *(const v8s*)&Ba[1][wx * 32 + mt * 16 + l15][q * 8];
        }
#pragma unroll
        for (int mt = 0; mt < 2; mt++)
#pragma unroll
            for (int nt = 0; nt < 2; nt++) {
                v4f c = ae[mt][nt];
                c = MFMA(af[mt][0], be[nt][0], c);
                c = MFMA(af[mt][0], be[nt][1], c);
                c = MFMA(af[mt][1], be[nt][0], c);
                ae[mt][nt] = c;
                v4f d = aa[mt][nt];
                d = MFMA(af[mt][0], ba[nt][0], d);
                d = MFMA(af[mt][0], ba[nt][1], d);
                d = MFMA(af[mt][1], ba[nt][0], d);
                aa[mt][nt] = d;
            }
        __syncthreads();
    }
    const float invB = 1.f / (float)B_;
#pragma unroll
    for (int mt = 0; mt < 2; mt++)
#pragma unroll
        for (int nt = 0; nt < 2; nt++) {
            int r0 = row0 + wy * 32 + mt * 16 + q * 4;
            int c  = col0 + wx * 32 + nt * 16 + l15;
            u16 hv[4][2];
#pragma unroll
            for (int r = 0; r < 4; r++) {
                size_t idx = (size_t)(r0 + r) * M_ + c;
                float old = A.memf[idx];  // block-private tile (same block every step): cached
                float nv = old * (1.f - ae[mt][nt][r] * invB) + aa[mt][nt][r] * invB;
                A.memf[idx] = nv;
                u16 h, m; split2(nv, h, m);
                sta_(A.mem_pl + idx, h); sta_(A.mem_pl + PL_MEM + idx, m);
                hv[r][0] = h; hv[r][1] = m;
                atomicAdd(&ssqs[r0 + r - row0], nv * nv);
            }
            size_t tb = (size_t)c * N_ + r0;
            st64_(A.memT_pl + tb, hv[0][0], hv[1][0], hv[2][0], hv[3][0]);
            st64_(A.memT_pl + PL_MEM + tb, hv[0][1], hv[1][1], hv[2][1], hv[3][1]);
        }
    __syncthreads();
    if (tid < 64) sta_(A.ssqp + (size_t)(row0 + tid) * 8 + bx, ssqs[tid]);
}

// ---------------- device: logits = (kh @ mem^T) * invn ----------------
__device__ void dev_logits(char* smc, int bx, int by, const NtmArgs& A) {
    typedef u16 (*T64)[64][40];
    T64 As = (T64)smc;
    T64 Bs = (T64)(smc + 10240);
    float* invn_s = (float*)(smc + 20480);
    const int tid = threadIdx.x, lane = tid & 63, w = tid >> 6;
    const int wy = w >> 1, wx = w & 1, q = lane >> 4, l15 = lane & 15;
    const int row0 = by * 64, col0 = bx * 64;  // row in [0,512), col=n
    if (tid < 64) {
        float s = 0.f;
#pragma unroll
        for (int j = 0; j < 8; j++) s += lda_(A.ssqp + (size_t)(col0 + tid) * 8 + j);
        invn_s[tid] = 1.f / (sqrtf(s) + EPS_);
    }
    uint4 ra[2], rb[2];
    auto loadAll = [&](int k0) {
#pragma unroll
        for (int j = 0; j < 2; j++) {
            int s = j * 256 + tid, p = s >> 8, rr = (s >> 2) & 63, kg = s & 3;
            ra[j] = ld16_(A.kh_pl + (size_t)p * PL_KH + (size_t)(row0 + rr) * M_ + k0 + kg * 8);
            rb[j] = ld16_(A.mem_pl + (size_t)p * PL_MEM + (size_t)(col0 + rr) * M_ + k0 + kg * 8);
        }
    };
    v4f acc[2][2] = {};
    loadAll(0);
    for (int k0 = 0; k0 < M_; k0 += 32) {
#pragma unroll
        for (int j = 0; j < 2; j++) {
            int s = j * 256 + tid, p = s >> 8, rr = (s >> 2) & 63, kg = s & 3;
            *(uint4*)&As[p][rr][kg * 8] = ra[j];
            *(uint4*)&Bs[p][rr][kg * 8] = rb[j];
        }
        __syncthreads();
        if (k0 + 32 < M_) loadAll(k0 + 32);
        v8s af[2][2], bf[2][2];
#pragma unroll
        for (int mt = 0; mt < 2; mt++) {
            af[mt][0] = *(const v8s*)&As[0][wy * 32 + mt * 16 + l15][q * 8];
            af[mt][1] = *(const v8s*)&As[1][wy * 32 + mt * 16 + l15][q * 8];
            bf[mt][0] = *(const v8s*)&Bs[0][wx * 32 + mt * 16 + l15][q * 8];
            bf[mt][1] = *(const v8s*)&Bs[1][wx * 32 + mt * 16 + l15][q * 8];
        }
#pragma unroll
        for (int mt = 0; mt < 2; mt++)
#pragma unroll
            for (int nt = 0; nt < 2; nt++) {
                v4f c = acc[mt][nt];
                c = MFMA(af[mt][0], bf[nt][0], c);
                c = MFMA(af[mt][0], bf[nt][1], c);
                c = MFMA(af[mt][1], bf[nt][0], c);
                acc[mt][nt] = c;
            }
        __syncthreads();
    }
#pragma unroll
    for (int mt = 0; mt < 2; mt++)
#pragma unroll
        for (int nt = 0; nt < 2; nt++) {
            int r0 = row0 + wy * 32 + mt * 16 + q * 4;
            int c  = col0 + wx * 32 + nt * 16 + l15;
            float in_ = invn_s[c - col0];
#pragma unroll
            for (int r = 0; r < 4; r++)
                sta_(A.logits + (size_t)(r0 + r) * N_ + c, acc[mt][nt][r] * in_);
        }
}

// ---------------- device: addressing tail ----------------
__device__ void dev_addr(char* smc, int row, const NtmArgs& A) {
    float* wgs = (float*)smc;           // N_ floats = 4096 B
    float* red = (float*)(smc + 4096);  // 8 floats
    int head = row >> 8, b = row & 255;
    const float* w6 = head ? A.w6r : A.w6w;
    const float* bias = head ? A.bhr : A.bhw;
    float* wf = head ? A.wrf : A.wwf;   // master row b: exclusively owned by this block
    int tid = threadIdx.x;
    float d0 = 0, d1 = 0, d2 = 0, d3 = 0, d4 = 0, d5 = 0, ssq = 0;
#pragma unroll
    for (int j = 0; j < 2; j++) {
        int k = tid + j * 256;
        float hv = lda_(A.hf + (size_t)b * H_ + k);
        const float* wk = w6 + k * 6;
        d0 += hv * wk[0]; d1 += hv * wk[1]; d2 += hv * wk[2];
        d3 += hv * wk[3]; d4 += hv * wk[4]; d5 += hv * wk[5];
        size_t ki = (size_t)row * M_ + k;
        float kv = bf2f(lda_(A.kh_pl + ki)) + bf2f(lda_(A.kh_pl + PL_KH + ki));
        ssq += kv * kv;
    }
    d0 = block_sum_(d0, red); d1 = block_sum_(d1, red); d2 = block_sum_(d2, red);
    d3 = block_sum_(d3, red); d4 = block_sum_(d4, red); d5 = block_sum_(d5, red);
    ssq = block_sum_(ssq, red);
    float beta = softplus_(d0 + bias[M_]);
    float g = sigm_(d1 + bias[M_ + 1]);
    float a0 = d2 + bias[M_ + 2], a1 = d3 + bias[M_ + 3], a2 = d4 + bias[M_ + 4];
    float mx3 = fmaxf(a0, fmaxf(a1, a2));
    float e0 = expf(a0 - mx3), e1 = expf(a1 - mx3), e2 = expf(a2 - mx3);
    float es = e0 + e1 + e2;
    float s0 = e0 / es, s1 = e1 / es, s2 = e2 / es;
    float gamma = 1.f + softplus_(d5 + bias[M_ + 5]);
    float rowsc = beta / (sqrtf(ssq) + EPS_);
    // logits row read: 16B contiguous per thread -> 2 x 8B sc1 loads
    const u64* lp = (const u64*)(A.logits + (size_t)row * N_ + tid * 4);
    u64 la = lda_(lp), lb = lda_(lp + 1);
    float l[4];
    l[0] = __uint_as_float((unsigned)la) * rowsc;
    l[1] = __uint_as_float((unsigned)(la >> 32)) * rowsc;
    l[2] = __uint_as_float((unsigned)lb) * rowsc;
    l[3] = __uint_as_float((unsigned)(lb >> 32)) * rowsc;
    float mx = fmaxf(fmaxf(l[0], l[1]), fmaxf(l[2], l[3]));
    mx = block_max_(mx, red);
    float ex[4], sum = 0.f;
#pragma unroll
    for (int j = 0; j < 4; j++) { ex[j] = expf(l[j] - mx); sum += ex[j]; }
    sum = block_sum_(sum, red);
    float inv = 1.f / sum;
    float wprev[4];
#pragma unroll
    for (int j = 0; j < 4; j++) wprev[j] = wf[(size_t)b * N_ + tid * 4 + j];
#pragma unroll
    for (int j = 0; j < 4; j++) wgs[tid * 4 + j] = g * ex[j] * inv + (1.f - g) * wprev[j];
    __syncthreads();
    float wp[4], psum = 0.f;
#pragma unroll
    for (int j = 0; j < 4; j++) {
        int n = tid * 4 + j;
        float wt = s0 * wgs[(n + 1) & (N_ - 1)] + s1 * wgs[n] + s2 * wgs[(n - 1) & (N_ - 1)];
        float v = expf(gamma * logf(wt));
        wp[j] = v; psum += v;
    }
    psum = block_sum_(psum, red);
    float invp = 1.f / (psum + EPS_);
#pragma unroll
    for (int j = 0; j < 4; j++) {
        int n = tid * 4 + j;
        float val = wp[j] * invp;
        wf[(size_t)b * N_ + n] = val;  // block-private master: cached
        u16 h, m; split2(val, h, m);
        if (head == 0) {
            size_t tb = (size_t)n * B_ + b;
            sta_(A.wwT_pl + tb, h); sta_(A.wwT_pl + PL_W + tb, m);
        } else {
            size_t idx = (size_t)b * N_ + n;
            sta_(A.wr_pl + idx, h); sta_(A.wr_pl + PL_W + idx, m);
        }
    }
}

// ---------------- persistent kernel: the whole T-loop ----------------
__global__ __launch_bounds__(256, 2) void ntm_loop(NtmArgs A) {
    __shared__ __align__(16) char sm[31232];
    const int bid = blockIdx.x;
    unsigned ep = 0;
    for (int t = 0; t < T_; t++) {
        // 1. mem update + row-ssq partials  [n x m, K=256]  (128 tiles, bx=xcd)
        if (bid < 128) dev_memupd(sm, bid, A);
        gsync(A.slots, A.flag, ++ep);
        // 2. r = wr @ mem  [256 x 512, K=1024]  (32 64x64 tiles, bx=xcd: memT slice/XCD)
        if (bid < 32) {
            int bx = bid & 7, by = bid >> 3;
            dev_gemm64<true, true>(sm, A.wr_pl, 1024, PL_W, A.memT_pl, 1024, PL_MEM, 1024,
                                   by * 64, bx * 64, EpiR{A.r_pl});
        }
        gsync(A.slots, A.flag, ++ep);
        // 3. h = tanh(xwx + r @ Wr + bh)  [256 x 512, K=512]  (32 64x64 tiles; WrT cached)
        if (bid < 32) {
            int bx = bid & 7, by = bid >> 3;
            dev_gemm64<true, false>(sm, A.r_pl, 512, PL_H, A.WrT, 512, PL_WRT, 512,
                                    by * 64, bx * 64,
                                    EpiH{A.out + (size_t)t * O_, A.bh, A.hf, A.h_pl});
        }
        gsync(A.slots, A.flag, ++ep);
        // 4. fused: h @ [Whw_k | Whr_k | Wo | Wea]  (320 tiles; 5 BigT slices per XCD, cached)
        if (bid < 320) {
            int g = bid & 7, idx = bid >> 3;           // idx 0..39
            int bx = g * 5 + idx % 5, by = idx / 5;    // bx 0..39, by 0..7
            dev_gemm32<true, false>(sm, A.h_pl, 512, PL_H, A.BigT, 512, PL_BIG, 512,
                                    by * 32, bx * 64,
                                    EpiFused{A.bhw, A.bhr, A.bo, A.bea, A.kh_pl,
                                             A.out + (size_t)t * O_, A.eT_pl, A.aT_pl});
        }
        gsync(A.slots, A.flag, ++ep);
        // 5. logits = (kh @ mem^T) * invn  [512 x 1024, K=512]  (128 tiles)
        if (bid < 128) {
            int g = bid & 7, idx = bid >> 3;           // idx 0..15
            int bx = g * 2 + (idx & 1), by = idx >> 1; // bx 0..15, by 0..7
            dev_logits(sm, bx, by, A);
        }
        gsync(A.slots, A.flag, ++ep);
        // 6. addressing tail -> ww/wr masters + planes  (512 rows, 1 per block)
        for (int row = bid; row < 2 * B_; row += NB_) dev_addr(sm, row, A);
        gsync(A.slots, A.flag, ++ep);
    }
}

// ---------------- generic 3-product MFMA GEMM (prologue use only) ----------------
template <int TM, class Epi>
__global__ __launch_bounds__(256) void gemm2(const u16* __restrict__ Ap, int lda, int apl,
                                             const u16* __restrict__ Bp, int ldb, int bpl,
                                             int K, Epi epi) {
    constexpr int AL = (TM * 32 * 2) / (256 * 8);
    constexpr int MT = TM / 32;
    __shared__ u16 As[2][TM][40];
    __shared__ u16 Bs[2][64][40];
    const int tid = threadIdx.x, lane = tid & 63, w = tid >> 6;
    const int wy = w >> 1, wx = w & 1, q = lane >> 4, l15 = lane & 15;
    const int row0 = blockIdx.y * TM, col0 = blockIdx.x * 64;
    uint4 ra[AL], rb[2];
    auto loadA = [&](int k0) {
#pragma unroll
        for (int j = 0; j < AL; j++) {
            int s = j * 256 + tid, p = s / (TM * 4), rr = (s >> 2) % TM, kg = s & 3;
            ra[j] = *(const uint4*)(Ap + (size_t)p * apl + (size_t)(row0 + rr) * lda + k0 + kg * 8);
        }
    };
    auto loadB = [&](int k0) {
#pragma unroll
        for (int j = 0; j < 2; j++) {
            int s = j * 256 + tid, p = s >> 8, rr = (s >> 2) & 63, kg = s & 3;
            rb[j] = *(const uint4*)(Bp + (size_t)p * bpl + (size_t)(col0 + rr) * ldb + k0 + kg * 8);
        }
    };
    v4f acc[MT][2] = {};
    loadA(0); loadB(0);
    for (int k0 = 0; k0 < K; k0 += 32) {
#pragma unroll
        for (int j = 0; j < AL; j++) {
            int s = j * 256 + tid, p = s / (TM * 4), rr = (s >> 2) % TM, kg = s & 3;
            *(uint4*)&As[p][rr][kg * 8] = ra[j];
        }
#pragma unroll
        for (int j = 0; j < 2; j++) {
            int s = j * 256 + tid, p = s >> 8, rr = (s >> 2) & 63, kg = s & 3;
            *(uint4*)&Bs[p][rr][kg * 8] = rb[j];
        }
        __syncthreads();
        if (k0 + 32 < K) { loadA(k0 + 32); loadB(k0 + 32); }
        v8s af[MT][2], bf[2][2];
#pragma unroll
        for (int mt = 0; mt < MT; mt++) {
            af[mt][0] = *(const v8s*)&As[0][wy * (TM / 2) + mt * 16 + l15][q * 8];
            af[mt][1] = *(const v8s*)&As[1][wy * (TM / 2) + mt * 16 + l15][q * 8];
        }
#pragma unroll
        for (int nt = 0; nt < 2; nt++) {
            bf[nt][0] = *(const v8s*)&Bs[0][wx * 32 + nt * 16 + l15][q * 8];
            bf[nt][1] = *(const v8s*)&Bs[1][wx * 32 + nt * 16 + l15][q * 8];
        }
#pragma unroll
        for (int mt = 0; mt < MT; mt++)
#pragma unroll
            for (int nt = 0; nt < 2; nt++) {
                v4f c = acc[mt][nt];
                c = MFMA(af[mt][0], bf[nt][0], c);
                c = MFMA(af[mt][0], bf[nt][1], c);
                c = MFMA(af[mt][1], bf[nt][0], c);
                acc[mt][nt] = c;
            }
        __syncthreads();
    }
#pragma unroll
    for (int mt = 0; mt < MT; mt++)
#pragma unroll
        for (int nt = 0; nt < 2; nt++)
            epi(row0 + wy * (TM / 2) + mt * 16 + q * 4, col0 + wx * 32 + nt * 16 + l15, acc[mt][nt]);
}

// ---------------- xwx GEMM: rows (t*256+b), A split from f32 on the fly, out -> d_out[b][t][:] ----------------
__global__ __launch_bounds__(256) void gemm2_xwx(const float* __restrict__ x, const u16* __restrict__ WxT,
                                                 float* __restrict__ outbuf) {
    __shared__ u16 As[2][64][40];
    __shared__ u16 Bs[2][64][40];
    const int tid = threadIdx.x, lane = tid & 63, w = tid >> 6;
    const int wy = w >> 1, wx = w & 1, q = lane >> 4, l15 = lane & 15;
    const int row0 = blockIdx.y * 64, col0 = blockIdx.x * 64;
    const int sr = tid >> 2, ss = (tid & 3) * 8;
    const int arow = row0 + sr, ab = arow & 255, at = arow >> 8;
    const float* Asrc = x + ((size_t)ab * T_ + at) * I_ + ss;
    v4f acc[2][2] = {};
    for (int k0 = 0; k0 < I_; k0 += 32) {
        float4 f0 = *(const float4*)(Asrc + k0);
        float4 f1 = *(const float4*)(Asrc + k0 + 4);
        float av8[8] = {f0.x, f0.y, f0.z, f0.w, f1.x, f1.y, f1.z, f1.w};
#pragma unroll
        for (int j = 0; j < 8; j++) {
            u16 h, m; split2(av8[j], h, m);
            As[0][sr][ss + j] = h; As[1][sr][ss + j] = m;
        }
#pragma unroll
        for (int p = 0; p < 2; p++)
            *(uint4*)&Bs[p][sr][ss] = *(const uint4*)&WxT[(size_t)p * PL_WXT + (size_t)(col0 + sr) * I_ + k0 + ss];
        __syncthreads();
        v8s af[2][2], bf[2][2];
#pragma unroll
        for (int mt = 0; mt < 2; mt++) {
            af[mt][0] = *(const v8s*)&As[0][wy * 32 + mt * 16 + l15][q * 8];
            af[mt][1] = *(const v8s*)&As[1][wy * 32 + mt * 16 + l15][q * 8];
            bf[mt][0] = *(const v8s*)&Bs[0][wx * 32 + mt * 16 + l15][q * 8];
            bf[mt][1] = *(const v8s*)&Bs[1][wx * 32 + mt * 16 + l15][q * 8];
        }
#pragma unroll
        for (int mt = 0; mt < 2; mt++)
#pragma unroll
            for (int nt = 0; nt < 2; nt++) {
                v4f c = acc[mt][nt];
                c = MFMA(af[mt][0], bf[nt][0], c);
                c = MFMA(af[mt][0], bf[nt][1], c);
                c = MFMA(af[mt][1], bf[nt][0], c);
                acc[mt][nt] = c;
            }
        __syncthreads();
    }
#pragma unroll
    for (int mt = 0; mt < 2; mt++)
#pragma unroll
        for (int nt = 0; nt < 2; nt++) {
            int r0 = row0 + wy * 32 + mt * 16 + q * 4;
            int c  = col0 + wx * 32 + nt * 16 + l15;
#pragma unroll
            for (int r = 0; r < 4; r++) {
                int row = r0 + r, b = row & 255, t = row >> 8;
                outbuf[((size_t)b * T_ + t) * O_ + c] = acc[mt][nt][r];
            }
        }
}

// ---------------- decomp: transpose + split2: in f32 [R][ldin] cols c0.. -> planes [C][R] ----------------
__global__ __launch_bounds__(256) void decomp_t(const float* __restrict__ in, int ldin, int c0,
                                                int R, u16* __restrict__ outp, int opl) {
    __shared__ float Ls[32][33];
    const int r0 = blockIdx.x * 32, cB = blockIdx.y * 32;
    const int tid = threadIdx.x;
    int lr = tid >> 3, lc = (tid & 7) * 4;
#pragma unroll
    for (int j = 0; j < 4; j++)
        Ls[lr][lc + j] = in[(size_t)(r0 + lr) * ldin + c0 + cB + lc + j];
    __syncthreads();
    int lc2 = tid >> 3, lr2 = (tid & 7) * 4;
    u16 hv[4], mv[4];
#pragma unroll
    for (int j = 0; j < 4; j++) split2(Ls[lr2 + j][lc2], hv[j], mv[j]);
    size_t base = (size_t)(cB + lc2) * R + r0 + lr2;
    *(ushort4*)&outp[0 * (size_t)opl + base] = make_ushort4(hv[0], hv[1], hv[2], hv[3]);
    *(ushort4*)&outp[1 * (size_t)opl + base] = make_ushort4(mv[0], mv[1], mv[2], mv[3]);
}

// ---------------- init / misc ----------------
__global__ __launch_bounds__(512) void wh6_kernel(const float* __restrict__ Whw, const float* __restrict__ Whr,
                                                  float* __restrict__ w6w, float* __restrict__ w6r,
                                                  unsigned* __restrict__ barz) {
    int k = threadIdx.x;
    if (blockIdx.x == 0) {
        for (int i = k; i < NB_ * 16 + 16; i += 512) barz[i] = 0u;  // 512 slots*16 + flag line
    }
    const float* src = blockIdx.x ? Whr : Whw;
    float* dst = blockIdx.x ? w6r : w6w;
#pragma unroll
    for (int j = 0; j < 6; j++) dst[k * 6 + j] = src[(size_t)k * (M_ + 6) + M_ + j];
}
__global__ __launch_bounds__(256) void init_mem(const float* __restrict__ mem0, float* __restrict__ memf,
                                                u16* __restrict__ mem_pl, u16* __restrict__ memT_pl) {
    int n = blockIdx.x;
    for (int c = threadIdx.x; c < M_; c += 256) {
        float v = mem0[(size_t)n * M_ + c];
        size_t idx = (size_t)n * M_ + c;
        memf[idx] = v;
        u16 h, m; split2(v, h, m);
        mem_pl[idx] = h; mem_pl[PL_MEM + idx] = m;
        size_t tb = (size_t)c * N_ + n;
        memT_pl[tb] = h; memT_pl[PL_MEM + tb] = m;
    }
}
__global__ __launch_bounds__(256) void init_w(const float* __restrict__ wr0, const float* __restrict__ ww0,
                                              float* __restrict__ wrf, float* __restrict__ wwf,
                                              u16* __restrict__ wr_pl, u16* __restrict__ wwT_pl) {
    int b = blockIdx.x;
    for (int n = threadIdx.x; n < N_; n += 256) {
        size_t idx = (size_t)b * N_ + n;
        float vw = ww0[idx]; wwf[idx] = vw;
        u16 h, m; split2(vw, h, m);
        size_t tb = (size_t)n * B_ + b;
        wwT_pl[tb] = h; wwT_pl[PL_W + tb] = m;
        float vr = wr0[idx]; wrf[idx] = vr;
        split2(vr, h, m);
        wr_pl[idx] = h; wr_pl[PL_W + idx] = m;
    }
}
__global__ __launch_bounds__(64) void init_h(const float* __restrict__ h0, float* __restrict__ hf,
                                             u16* __restrict__ hp) {
    int b = blockIdx.x;
    for (int c = threadIdx.x; c < H_; c += 64) {
        size_t idx = (size_t)b * H_ + c;
        float v = h0[idx];
        hf[idx] = v;
        u16 h, m; split2(v, h, m);
        hp[idx] = h; hp[PL_H + idx] = m;
    }
}

// ---------------- host ----------------
extern "C" void kernel_launch(void* const* d_in, const int* in_sizes, int n_in,
                              void* d_out, int out_size, void* d_ws, size_t ws_size,
                              hipStream_t stream) {
    (void)in_sizes; (void)n_in; (void)out_size; (void)ws_size;
    const float* x    = (const float*)d_in[0];
    const float* mem0 = (const float*)d_in[1];
    const float* wr0  = (const float*)d_in[2];
    const float* ww0  = (const float*)d_in[3];
    const float* h0   = (const float*)d_in[4];
    const float* Wx   = (const float*)d_in[5];
    const float* Wr   = (const float*)d_in[6];
    const float* bh   = (const float*)d_in[7];
    const float* Whr  = (const float*)d_in[8];
    const float* bhr  = (const float*)d_in[9];
    const float* Whw  = (const float*)d_in[10];
    const float* bhw  = (const float*)d_in[11];
    const float* Wea  = (const float*)d_in[12];
    const float* bea  = (const float*)d_in[13];
    const float* Wo   = (const float*)d_in[14];
    const float* bo   = (const float*)d_in[15];
    float* out = (float*)d_out;

    char* wsb = (char*)d_ws;
    size_t off = 0;
    auto carveU = [&](size_t elems) { u16* p = (u16*)(wsb + off); off += elems * sizeof(u16); return p; };
    u16* BigT    = carveU(2 * (size_t)PL_BIG);
    u16* WxT     = carveU(2 * (size_t)PL_WXT);
    u16* WrT     = carveU(2 * (size_t)PL_WRT);
    u16* mem_pl  = carveU(2 * (size_t)PL_MEM);
    u16* memT_pl = carveU(2 * (size_t)PL_MEM);
    u16* wwT_pl  = carveU(2 * (size_t)PL_W);
    u16* wr_pl   = carveU(2 * (size_t)PL_W);
    u16* h_pl    = carveU(2 * (size_t)PL_H);
    u16* r_pl    = carveU(2 * (size_t)PL_H);
    u16* eT_pl   = carveU(2 * (size_t)PL_H);
    u16* aT_pl   = carveU(2 * (size_t)PL_H);
    u16* kh_pl   = carveU(2 * (size_t)PL_KH);
    auto carveF = [&](size_t elems) { float* p = (float*)(wsb + off); off += elems * sizeof(float); return p; };
    float* memf   = carveF((size_t)N_ * M_);
    float* wwf    = carveF((size_t)B_ * N_);
    float* wrf    = carveF((size_t)B_ * N_);
    float* hf     = carveF((size_t)B_ * H_);
    float* logits = carveF((size_t)2 * B_ * N_);
    float* ssqp   = carveF((size_t)N_ * 8);
    float* w6w    = carveF(H_ * 6);
    float* w6r    = carveF(H_ * 6);
    // barrier region: NB_ slots (64B apart) + flag on its own line
    off = (off + 127) & ~(size_t)127;
    unsigned* slots = (unsigned*)(wsb + off);           // slots[NB_*16]
    unsigned* flag  = slots + NB_ * 16;                 // 64B-aligned
    off += (NB_ * 16 + 16) * sizeof(unsigned) + 64;

    // ---- prologue: weight decomposition + state init (also zeroes the barrier region) ----
    decomp_t<<<dim3(16, 16), 256, 0, stream>>>(Whw, M_ + 6, 0, 512, BigT, PL_BIG);                       // rows 0-511
    decomp_t<<<dim3(16, 16), 256, 0, stream>>>(Whr, M_ + 6, 0, 512, BigT + (size_t)512 * 512, PL_BIG);   // rows 512-1023
    decomp_t<<<dim3(16, 16), 256, 0, stream>>>(Wo, 512, 0, 512, BigT + (size_t)1024 * 512, PL_BIG);      // rows 1024-1535
    decomp_t<<<dim3(16, 32), 256, 0, stream>>>(Wea, 1024, 0, 512, BigT + (size_t)1536 * 512, PL_BIG);    // rows 1536-2559
    decomp_t<<<dim3(16, 16), 256, 0, stream>>>(Wx, 512, 0, 512, WxT, PL_WXT);
    decomp_t<<<dim3(16, 16), 256, 0, stream>>>(Wr, 512, 0, 512, WrT, PL_WRT);
    wh6_kernel<<<2, 512, 0, stream>>>(Whw, Whr, w6w, w6r, slots);
    init_mem<<<N_, 256, 0, stream>>>(mem0, memf, mem_pl, memT_pl);
    init_w<<<B_, 256, 0, stream>>>(wr0, ww0, wrf, wwf, wr_pl, wwT_pl);
    init_h<<<B_, 64, 0, stream>>>(h0, hf, h_pl);
    // xwx for all (t,b) -> stored in d_out slots [b][t][:]
    gemm2_xwx<<<dim3(8, 512), 256, 0, stream>>>(x, WxT, out);
    // ea for step 0 from h0
    gemm2<32, EpiEA0><<<dim3(16, 8), 256, 0, stream>>>(
        h_pl, 512, PL_H, BigT + (size_t)1536 * 512, 512, PL_BIG, 512, EpiEA0{bea, eT_pl, aT_pl});

    // ---- the entire T-loop: one persistent kernel, fence-free, wide-sc1 traffic ----
    NtmArgs A;
    A.BigT = BigT; A.WxT = WxT; A.WrT = WrT;
    A.mem_pl = mem_pl; A.memT_pl = memT_pl; A.wwT_pl = wwT_pl; A.wr_pl = wr_pl;
    A.h_pl = h_pl; A.r_pl = r_pl; A.eT_pl = eT_pl; A.aT_pl = aT_pl; A.kh_pl = kh_pl;
    A.memf = memf; A.wwf = wwf; A.wrf = wrf; A.hf = hf; A.logits = logits; A.ssqp = ssqp;
    A.w6w = w6w; A.w6r = w6r; A.bh = bh; A.bhw = bhw; A.bhr = bhr; A.bea = bea; A.bo = bo;
    A.out = out;
    A.slots = slots;
    A.flag = flag;
    ntm_loop<<<dim3(NB_), dim3(256), 0, stream>>>(A);
}